// Round 19
// baseline (934.436 us; speedup 1.0000x reference)
//
#include <hip/hip_runtime.h>
#include <hip/hip_bf16.h>
#include <math.h>

#define N_ATOMS 50000
#define N_EDGES 1600000
#define FDIM 128
#define NB 25
#define CUTOFF_F 5.0f
#define PI_OVER_CUTOFF 0.6283185307179586f
#define NBLK 1024 // persistent blocks for edge kernel (4/CU x 256)
#define RB 196    // radix buckets = dst>>8
#define P1B 782   // pass-1 blocks = ceil(1.6M / 2048)

typedef __bf16 bf16x8 __attribute__((ext_vector_type(8)));
typedef float f32x4 __attribute__((ext_vector_type(4)));

__device__ __forceinline__ float swish_f(float v) {
    return v * __builtin_amdgcn_rcpf(1.0f + __expf(-v));
}

__device__ __forceinline__ unsigned short bfbits(__bf16 x) {
    union { __bf16 b; unsigned short u; } c; c.b = x; return c.u;
}

// ---------------- LDS-radix group-by-dst (r18-proven) ----------------

__global__ __launch_bounds__(256) void radix1_hist_kernel(
    const int* __restrict__ dst, int* __restrict__ ebkt, int* __restrict__ gh)
{
    __shared__ int lh[RB];
    const int t = threadIdx.x;
    const int b = blockIdx.x;
    for (int i = t; i < RB; i += 256) lh[i] = 0;
    __syncthreads();
    const int base = b * 2048;
    #pragma unroll
    for (int it = 0; it < 8; ++it) {
        int i = base + it * 256 + t;
        if (i < N_EDGES) {
            int bkt = dst[i] >> 8;
            int rank = atomicAdd(&lh[bkt], 1);
            ebkt[i] = (bkt << 11) | rank;
        }
    }
    __syncthreads();
    for (int i = t; i < RB; i += 256) gh[i * P1B + b] = lh[i];
}

__global__ __launch_bounds__(256) void scan_buckets_kernel(
    const int* __restrict__ gh, int* __restrict__ off, int* __restrict__ bt)
{
    __shared__ int sa[256], sb[256];
    const int k = blockIdx.x;
    const int t = threadIdx.x;
    const int base = k * P1B;
    int v[4]; int s = 0;
    #pragma unroll
    for (int j = 0; j < 4; ++j) {
        int b = t * 4 + j;
        v[j] = (b < P1B) ? gh[base + b] : 0;
        s += v[j];
    }
    sa[t] = s;
    __syncthreads();
    int* cur = sa; int* nxt = sb;
    for (int o = 1; o < 256; o <<= 1) {
        int val = cur[t];
        if (t >= o) val += cur[t - o];
        nxt[t] = val;
        __syncthreads();
        int* tmp = cur; cur = nxt; nxt = tmp;
    }
    int run = cur[t] - s;
    #pragma unroll
    for (int j = 0; j < 4; ++j) {
        int b = t * 4 + j;
        if (b < P1B) off[base + b] = run;
        run += v[j];
    }
    if (t == 255) bt[k] = cur[t];
}

__global__ __launch_bounds__(256) void scan_base_kernel(int* __restrict__ bt) {
    __shared__ int sa[256], sb[256];
    const int t = threadIdx.x;
    int v = (t < RB) ? bt[t] : 0;
    sa[t] = v;
    __syncthreads();
    int* cur = sa; int* nxt = sb;
    for (int o = 1; o < 256; o <<= 1) {
        int val = cur[t];
        if (t >= o) val += cur[t - o];
        nxt[t] = val;
        __syncthreads();
        int* tmp = cur; cur = nxt; nxt = tmp;
    }
    if (t < RB) bt[t] = cur[t] - v;
    if (t == RB - 1) bt[RB] = cur[t];
}

__global__ __launch_bounds__(256) void radix1_place_kernel(
    const int* __restrict__ ebkt, const int* __restrict__ off,
    const int* __restrict__ bstart, int* __restrict__ ebuf1)
{
    __shared__ int obs[RB];
    const int t = threadIdx.x;
    const int b = blockIdx.x;
    if (t < RB) obs[t] = bstart[t] + off[t * P1B + b];
    __syncthreads();
    const int base = b * 2048;
    #pragma unroll
    for (int it = 0; it < 8; ++it) {
        int i = base + it * 256 + t;
        if (i < N_EDGES) {
            int p = ebkt[i];
            ebuf1[obs[p >> 11] + (p & 2047)] = i;
        }
    }
}

__global__ __launch_bounds__(1024) void radix2_kernel(
    const int* __restrict__ ebuf1, const int* __restrict__ dst,
    const int* __restrict__ bstart, int* __restrict__ perm)
{
    __shared__ int lh2[256], sa[256], sb[256], cur2[256];
    const int t = threadIdx.x;
    const int k = blockIdx.x;
    const int start = bstart[k];
    const int end = bstart[k + 1];
    if (t < 256) lh2[t] = 0;
    __syncthreads();
    for (int i = start + t; i < end; i += 1024) {
        int e = ebuf1[i];
        atomicAdd(&lh2[dst[e] & 255], 1);
    }
    __syncthreads();
    if (t < 256) sa[t] = lh2[t];
    __syncthreads();
    int* cur = sa; int* nxt = sb;
    for (int o = 1; o < 256; o <<= 1) {
        if (t < 256) {
            int val = cur[t];
            if (t >= o) val += cur[t - o];
            nxt[t] = val;
        }
        __syncthreads();
        int* tmp = cur; cur = nxt; nxt = tmp;
    }
    if (t < 256) cur2[t] = cur[t] - lh2[t];
    __syncthreads();
    for (int i = start + t; i < end; i += 1024) {
        int e = ebuf1[i];
        int r = atomicAdd(&cur2[dst[e] & 255], 1);
        perm[start + r] = e;
    }
}

// ---------------- weight packing ----------------
// perm2: permute K rows by inv-pi so GEMM2's A-frag is register-local after
// swapped GEMM1 (k' = 32*(n>>1) + 8*kgrp + 4*(n&1) + r; read row invpi(k')).
// bias: if non-null, logical row K_eff gets bias (GEMM1 bias fold; A supplies 1.0).

__global__ void pack_b_kernel(const float* __restrict__ W, const float* __restrict__ bias,
                              __bf16* __restrict__ out, int K_eff, int KS, int perm2)
{
    int idx = blockIdx.x * 256 + threadIdx.x;
    int total = KS * 8 * 64 * 8;
    if (idx >= total) return;
    int j  = idx & 7;
    int l  = (idx >> 3) & 63;
    int n  = (idx >> 9) & 7;
    int ks = idx >> 12;
    int k   = ks * 32 + ((l >> 4) << 3) + j;   // logical k'
    int col = (n << 4) + (l & 15);
    int kr = k;
    if (perm2) kr = 32 * (k >> 5) + 16 * ((k >> 2) & 1) + 4 * ((k >> 3) & 3) + (k & 3);
    float v;
    if (kr < K_eff) v = W[kr * FDIM + col];
    else if (bias && kr == K_eff) v = bias[col];
    else v = 0.0f;
    out[idx] = (__bf16)v;
}

// ---------------- MFMA node GEMM (r12-proven) ----------------

__global__ __launch_bounds__(512, 2) void node_mfma_kernel(
    const float* __restrict__ A, const __bf16* __restrict__ wp,
    const float* __restrict__ bias,
    __bf16* __restrict__ out_bf, float* __restrict__ out_f32,
    int do_swish)
{
    __shared__ __bf16 ws_[16384];   // 32 KB packed B

    const int t = threadIdx.x;
    const int l = t & 63;
    const int w = t >> 6;
    const int lrow = l & 15;
    const int kgrp = l >> 4;

    {
        const int4* g = (const int4*)wp;
        int4* s = (int4*)ws_;
        for (int i = t; i < 2048; i += 512) s[i] = g[i];
    }
    float br[8];
    #pragma unroll
    for (int n = 0; n < 8; ++n) br[n] = bias ? bias[(n << 4) + lrow] : 0.0f;
    __syncthreads();

    const int tile = blockIdx.x * 8 + w;
    if (tile >= N_ATOMS / 16) return;
    const int row0 = tile << 4;

    bf16x8 af[4];
    const float* ap = A + (size_t)(row0 + lrow) * FDIM + (kgrp << 3);
    #pragma unroll
    for (int ks = 0; ks < 4; ++ks) {
        float4 lo = *(const float4*)(ap + (ks << 5));
        float4 hi = *(const float4*)(ap + (ks << 5) + 4);
        af[ks][0] = (__bf16)lo.x; af[ks][1] = (__bf16)lo.y;
        af[ks][2] = (__bf16)lo.z; af[ks][3] = (__bf16)lo.w;
        af[ks][4] = (__bf16)hi.x; af[ks][5] = (__bf16)hi.y;
        af[ks][6] = (__bf16)hi.z; af[ks][7] = (__bf16)hi.w;
    }

    const f32x4 zero = {0.f, 0.f, 0.f, 0.f};
    f32x4 acc[8];
    #pragma unroll
    for (int n = 0; n < 8; ++n) acc[n] = zero;

    #pragma unroll
    for (int ks = 0; ks < 4; ++ks) {
        bf16x8 bfr[8];
        #pragma unroll
        for (int n = 0; n < 8; ++n)
            bfr[n] = *(const bf16x8*)((const char*)ws_ + (((ks << 3) + n) << 10) + (l << 4));
        #pragma unroll
        for (int n = 0; n < 8; ++n)
            acc[n] = __builtin_amdgcn_mfma_f32_16x16x32_bf16(af[ks], bfr[n], acc[n], 0, 0, 0);
    }

    if (out_bf) {
        #pragma unroll
        for (int r = 0; r < 4; ++r) {
            bf16x8 o;
            #pragma unroll
            for (int n = 0; n < 8; ++n) {
                float v = acc[n][r] + br[n];
                if (do_swish) v = swish_f(v);
                o[n] = (__bf16)v;
            }
            *(bf16x8*)&out_bf[(size_t)(row0 + (kgrp << 2) + r) * FDIM + (lrow << 3)] = o;
        }
    } else {
        #pragma unroll
        for (int r = 0; r < 4; ++r) {
            int orow = row0 + (kgrp << 2) + r;
            #pragma unroll
            for (int n = 0; n < 8; ++n) {
                float v = acc[n][r] + br[n];
                if (do_swish) v = swish_f(v);
                out_f32[(size_t)orow * FDIM + (n << 4) + lrow] = v;
            }
        }
    }
}

// ---------------- persistent-wave MFMA edge kernel (LDS-free H path) ----------------
// Swapped GEMM1: h_n = mfma(W1^T_frag, fij_frag) -> lane holds 32 channels of
// ITS OWN edge (col=lane&15). With W2 rows packed by inv-pi, GEMM2's A-frag is
// a register concat of the lane's own h values: a2[ks] = {h_{2ks}, h_{2ks+1}}.
// No hs LDS, no ds_writes, no lgkm chain. b1 folded into GEMM1 (fij[25]=1.0,
// W1 row 25 = b1). LDS = w2s only (32 KB) -> 256-thr blocks, 4 blocks/CU.

struct TileReg {
    float4 f0, f1;       // this lane's fij A-fragment data
    int   se_own, de_own;
    float rij_own;
};

__global__ __launch_bounds__(256, 4) void edge_kernel(
    const float* __restrict__ fij, const float* __restrict__ rij,
    const int* __restrict__ src, const int* __restrict__ dst,
    const int* __restrict__ perm,
    const __bf16* __restrict__ w1p,
    const __bf16* __restrict__ w2p, const float* __restrict__ b2,
    const __bf16* __restrict__ xb, float* __restrict__ agg)
{
    __shared__ __bf16 w2s[16384];       // 32 KB: W2 B-fragments (perm2-packed)

    const int t = threadIdx.x;
    const int l = t & 63;
    const int w = t >> 6;               // 0..3
    const int lrow = l & 15;
    const int kgrp = l >> 4;

    {
        const int4* g2 = (const int4*)w2p;
        int4* s2 = (int4*)w2s;
        for (int i = t; i < 2048; i += 256) s2[i] = g2[i];
    }

    bf16x8 w1f[8];
    float b2r[8];
    #pragma unroll
    for (int n = 0; n < 8; ++n) {
        w1f[n] = *(const bf16x8*)(w1p + (((n << 6) + l) << 3));
        b2r[n] = b2[(n << 4) + lrow];
    }
    __syncthreads();   // w2s ready; last barrier in the kernel

    const f32x4 zero = {0.f, 0.f, 0.f, 0.f};

    const int gw = blockIdx.x * 4 + w;   // global wave id
    const int NW = NBLK * 4;
    const int NT = N_EDGES / 16;
    if (gw >= NT) return;

    // fij gather; k=25 slot carries 1.0 (bias multiplier for folded b1)
    #define GATHER(T, pv) do { \
        const float* fp_ = fij + (size_t)(pv) * NB; \
        if (kgrp < 3) { \
            T.f0 = *(const float4*)(fp_ + (kgrp << 3)); \
            T.f1 = *(const float4*)(fp_ + (kgrp << 3) + 4); \
        } else { \
            T.f0 = make_float4(fp_[24], 1.0f, 0.f, 0.f); \
            T.f1 = make_float4(0.f, 0.f, 0.f, 0.f); \
        } \
        T.se_own = src[pv]; \
        T.de_own = dst[pv]; \
        T.rij_own = rij[pv]; \
    } while (0)

    TileReg cur, nxt;
    int pvB;
    {
        int pvA = perm[((size_t)gw << 4) + lrow];
        GATHER(cur, pvA);
        int i2 = gw + NW; i2 = (i2 < NT) ? i2 : (NT - 1);
        pvB = perm[((size_t)i2 << 4) + lrow];
    }

    for (int tb = gw; tb < NT; tb += NW) {
        // ---- (1) epilogue prep for CUR: shfls + xv loads FIRST (vmem head) ----
        float Cf_own = (cur.rij_own < CUTOFF_F)
                     ? 0.5f * (__cosf(cur.rij_own * PI_OVER_CUTOFF) + 1.0f) : 0.0f;
        int se4[4], de4[4]; float Cf[4];
        #pragma unroll
        for (int r = 0; r < 4; ++r) {
            se4[r] = __shfl(cur.se_own, (kgrp << 2) + r);
            Cf[r]  = __shfl(Cf_own, (kgrp << 2) + r);
            de4[r] = __shfl(cur.de_own, (kgrp << 2) + r);
        }
        bf16x8 xv4[4];
        #pragma unroll
        for (int r = 0; r < 4; ++r)
            xv4[r] = *(const bf16x8*)&xb[(size_t)se4[r] * FDIM + (lrow << 3)];

        // ---- (2) next-tile gathers AFTER xv (pad xv's vmcnt slack) ----
        GATHER(nxt, pvB);
        int i3 = tb + 2 * NW; i3 = (i3 < NT) ? i3 : (NT - 1);
        pvB = perm[((size_t)i3 << 4) + lrow];

        // ---- (3) GEMM1 (swapped): lane gets 32 channels of its own edge ----
        bf16x8 a;
        a[0] = (__bf16)cur.f0.x; a[1] = (__bf16)cur.f0.y;
        a[2] = (__bf16)cur.f0.z; a[3] = (__bf16)cur.f0.w;
        a[4] = (__bf16)cur.f1.x; a[5] = (__bf16)cur.f1.y;
        a[6] = (__bf16)cur.f1.z; a[7] = (__bf16)cur.f1.w;

        unsigned pk0[8], pk1[8];
        #pragma unroll
        for (int n = 0; n < 8; ++n) {
            f32x4 h = __builtin_amdgcn_mfma_f32_16x16x32_bf16(w1f[n], a, zero, 0, 0, 0);
            __bf16 q0 = (__bf16)swish_f(h[0]);
            __bf16 q1 = (__bf16)swish_f(h[1]);
            __bf16 q2 = (__bf16)swish_f(h[2]);
            __bf16 q3 = (__bf16)swish_f(h[3]);
            pk0[n] = ((unsigned)bfbits(q1) << 16) | bfbits(q0);
            pk1[n] = ((unsigned)bfbits(q3) << 16) | bfbits(q2);
        }

        // ---- (4) GEMM2: A-frag = register concat (W2 rows inv-pi packed) ----
        f32x4 acc[8];
        #pragma unroll
        for (int n = 0; n < 8; ++n) acc[n] = zero;

        #pragma unroll
        for (int ks = 0; ks < 4; ++ks) {
            union { unsigned u[4]; bf16x8 v; } A2;
            A2.u[0] = pk0[2 * ks];
            A2.u[1] = pk1[2 * ks];
            A2.u[2] = pk0[2 * ks + 1];
            A2.u[3] = pk1[2 * ks + 1];
            bf16x8 bfr[8];
            #pragma unroll
            for (int n = 0; n < 8; ++n)
                bfr[n] = *(const bf16x8*)((const char*)w2s + (((ks << 3) + n) << 10) + (l << 4));
            #pragma unroll
            for (int n = 0; n < 8; ++n)
                acc[n] = __builtin_amdgcn_mfma_f32_16x16x32_bf16(A2.v, bfr[n], acc[n], 0, 0, 0);
        }

        // ---- (5) Epilogue: uni fast path + run-compressed atomics ----
        int d0 = __shfl(cur.de_own, 0);
        bool uni = __all(cur.de_own == d0);

        if (uni) {
            const size_t dbase = (size_t)d0 * FDIM;
            #pragma unroll
            for (int n = 0; n < 8; ++n) {
                float s = 0.f;
                #pragma unroll
                for (int r = 0; r < 4; ++r)
                    s += (float)xv4[r][n] * (acc[n][r] + b2r[n]) * Cf[r];
                s += __shfl_xor(s, 16);
                s += __shfl_xor(s, 32);
                if (kgrp == 0) unsafeAtomicAdd(&agg[dbase + (n << 4) + lrow], s);
            }
        } else {
            const bool brk0 = (de4[0] != de4[1]);
            const bool brk1 = (de4[1] != de4[2]);
            const bool brk2 = (de4[2] != de4[3]);
            #pragma unroll
            for (int n = 0; n < 8; ++n) {
                int col = (n << 4) + lrow;
                float m[4];
                #pragma unroll
                for (int r = 0; r < 4; ++r)
                    m[r] = (float)xv4[r][n] * (acc[n][r] + b2r[n]) * Cf[r];
                float run = m[0];
                if (brk0) { unsafeAtomicAdd(&agg[(size_t)de4[0] * FDIM + col], run); run = 0.f; }
                run += m[1];
                if (brk1) { unsafeAtomicAdd(&agg[(size_t)de4[1] * FDIM + col], run); run = 0.f; }
                run += m[2];
                if (brk2) { unsafeAtomicAdd(&agg[(size_t)de4[2] * FDIM + col], run); run = 0.f; }
                run += m[3];
                unsafeAtomicAdd(&agg[(size_t)de4[3] * FDIM + col], run);
            }
        }

        cur = nxt;
    }
    #undef GATHER
}

extern "C" void kernel_launch(void* const* d_in, const int* in_sizes, int n_in,
                              void* d_out, int out_size, void* d_ws, size_t ws_size,
                              hipStream_t stream)
{
    const float* feat   = (const float*)d_in[0];
    const float* fij    = (const float*)d_in[1];
    const float* rij    = (const float*)d_in[2];
    const int*   src    = (const int*)d_in[3];
    const int*   dst    = (const int*)d_in[4];
    const float* W_in2f = (const float*)d_in[5];
    const float* W_f1   = (const float*)d_in[6];
    const float* b_f1   = (const float*)d_in[7];
    const float* W_f2   = (const float*)d_in[8];
    const float* b_f2   = (const float*)d_in[9];
    const float* W_out  = (const float*)d_in[10];
    const float* b_out  = (const float*)d_in[11];
    float* out = (float*)d_out;

    // ws layout, total 33,333,696 B (r18-proven)
    char* ws = (char*)d_ws;
    __bf16* xb    = (__bf16*)ws;                  // 12,800,000 B
    __bf16* w1p   = (__bf16*)(ws + 12800000);     //      8,192 B
    __bf16* w2p   = (__bf16*)(ws + 12808192);     //     32,768 B
    __bf16* winp  = (__bf16*)(ws + 12840960);     //     32,768 B
    __bf16* woutp = (__bf16*)(ws + 12873728);     //     32,768 B
    int*    bt    = (int*)(ws + 12906496);        //      1,024 B
    int*    gh    = (int*)(ws + 12907520);        //    613,088 B
    int*    off   = (int*)(ws + 13520608);        //    613,088 B
    int*    ebkt  = (int*)(ws + 14133696);        //  6,400,000 B
    int*    ebuf1 = (int*)(ws + 20533696);        //  6,400,000 B
    int*    perm  = (int*)(ws + 26933696);        //  6,400,000 B
    float*  agg   = out;                          // accumulate into d_out

    hipMemsetAsync(agg, 0, (size_t)N_ATOMS * FDIM * sizeof(float), stream);

    // LDS-radix group-by-dst (no global atomics)
    radix1_hist_kernel<<<P1B, 256, 0, stream>>>(dst, ebkt, gh);
    scan_buckets_kernel<<<RB, 256, 0, stream>>>(gh, off, bt);
    scan_base_kernel<<<1, 256, 0, stream>>>(bt);
    radix1_place_kernel<<<P1B, 256, 0, stream>>>(ebkt, off, bt, ebuf1);
    radix2_kernel<<<RB, 1024, 0, stream>>>(ebuf1, dst, bt, perm);

    // W1: bias folded at logical row 25; W2: rows permuted by inv-pi
    pack_b_kernel<<<(4096 + 255) / 256, 256, 0, stream>>>(W_f1, b_f1, w1p, NB, 1, 0);
    pack_b_kernel<<<(16384 + 255) / 256, 256, 0, stream>>>(W_f2, nullptr, w2p, 128, 4, 1);
    pack_b_kernel<<<(16384 + 255) / 256, 256, 0, stream>>>(W_in2f, nullptr, winp, 128, 4, 0);
    pack_b_kernel<<<(16384 + 255) / 256, 256, 0, stream>>>(W_out, nullptr, woutp, 128, 4, 0);

    // x = feat @ W_in2f  -> xb (bf16, permuted)
    node_mfma_kernel<<<(N_ATOMS / 16 + 7) / 8, 512, 0, stream>>>(
        feat, winp, nullptr, xb, nullptr, 0);

    edge_kernel<<<NBLK, 256, 0, stream>>>(
        fij, rij, src, dst, perm, w1p, w2p, b_f2, xb, agg);

    // out = swish(agg @ W_out + b_out)  (in-place per 16-row tile)
    node_mfma_kernel<<<(N_ATOMS / 16 + 7) / 8, 512, 0, stream>>>(
        agg, woutp, b_out, nullptr, out, 1);
}

// Round 20
// 537.303 us; speedup vs baseline: 1.7391x; 1.7391x over previous
//
#include <hip/hip_runtime.h>
#include <hip/hip_bf16.h>
#include <math.h>

#define N_ATOMS 50000
#define N_EDGES 1600000
#define FDIM 128
#define NB 25
#define CUTOFF_F 5.0f
#define PI_OVER_CUTOFF 0.6283185307179586f
#define NBLK 1024 // persistent blocks for edge kernel
#define RB 196    // radix buckets = dst>>8
#define P1B 782   // pass-1 blocks = ceil(1.6M / 2048)

typedef __bf16 bf16x8 __attribute__((ext_vector_type(8)));
typedef float f32x4 __attribute__((ext_vector_type(4)));

__device__ __forceinline__ float swish_f(float v) {
    return v * __builtin_amdgcn_rcpf(1.0f + __expf(-v));
}

__device__ __forceinline__ unsigned short bfbits(__bf16 x) {
    union { __bf16 b; unsigned short u; } c; c.b = x; return c.u;
}

// ---------------- LDS-radix group-by-dst (r18-proven) ----------------

__global__ __launch_bounds__(256) void radix1_hist_kernel(
    const int* __restrict__ dst, int* __restrict__ ebkt, int* __restrict__ gh)
{
    __shared__ int lh[RB];
    const int t = threadIdx.x;
    const int b = blockIdx.x;
    for (int i = t; i < RB; i += 256) lh[i] = 0;
    __syncthreads();
    const int base = b * 2048;
    #pragma unroll
    for (int it = 0; it < 8; ++it) {
        int i = base + it * 256 + t;
        if (i < N_EDGES) {
            int bkt = dst[i] >> 8;
            int rank = atomicAdd(&lh[bkt], 1);
            ebkt[i] = (bkt << 11) | rank;
        }
    }
    __syncthreads();
    for (int i = t; i < RB; i += 256) gh[i * P1B + b] = lh[i];
}

__global__ __launch_bounds__(256) void scan_buckets_kernel(
    const int* __restrict__ gh, int* __restrict__ off, int* __restrict__ bt)
{
    __shared__ int sa[256], sb[256];
    const int k = blockIdx.x;
    const int t = threadIdx.x;
    const int base = k * P1B;
    int v[4]; int s = 0;
    #pragma unroll
    for (int j = 0; j < 4; ++j) {
        int b = t * 4 + j;
        v[j] = (b < P1B) ? gh[base + b] : 0;
        s += v[j];
    }
    sa[t] = s;
    __syncthreads();
    int* cur = sa; int* nxt = sb;
    for (int o = 1; o < 256; o <<= 1) {
        int val = cur[t];
        if (t >= o) val += cur[t - o];
        nxt[t] = val;
        __syncthreads();
        int* tmp = cur; cur = nxt; nxt = tmp;
    }
    int run = cur[t] - s;
    #pragma unroll
    for (int j = 0; j < 4; ++j) {
        int b = t * 4 + j;
        if (b < P1B) off[base + b] = run;
        run += v[j];
    }
    if (t == 255) bt[k] = cur[t];
}

__global__ __launch_bounds__(256) void scan_base_kernel(int* __restrict__ bt) {
    __shared__ int sa[256], sb[256];
    const int t = threadIdx.x;
    int v = (t < RB) ? bt[t] : 0;
    sa[t] = v;
    __syncthreads();
    int* cur = sa; int* nxt = sb;
    for (int o = 1; o < 256; o <<= 1) {
        int val = cur[t];
        if (t >= o) val += cur[t - o];
        nxt[t] = val;
        __syncthreads();
        int* tmp = cur; cur = nxt; nxt = tmp;
    }
    if (t < RB) bt[t] = cur[t] - v;
    if (t == RB - 1) bt[RB] = cur[t];
}

__global__ __launch_bounds__(256) void radix1_place_kernel(
    const int* __restrict__ ebkt, const int* __restrict__ off,
    const int* __restrict__ bstart, int* __restrict__ ebuf1)
{
    __shared__ int obs[RB];
    const int t = threadIdx.x;
    const int b = blockIdx.x;
    if (t < RB) obs[t] = bstart[t] + off[t * P1B + b];
    __syncthreads();
    const int base = b * 2048;
    #pragma unroll
    for (int it = 0; it < 8; ++it) {
        int i = base + it * 256 + t;
        if (i < N_EDGES) {
            int p = ebkt[i];
            ebuf1[obs[p >> 11] + (p & 2047)] = i;
        }
    }
}

__global__ __launch_bounds__(1024) void radix2_kernel(
    const int* __restrict__ ebuf1, const int* __restrict__ dst,
    const int* __restrict__ bstart, int* __restrict__ perm)
{
    __shared__ int lh2[256], sa[256], sb[256], cur2[256];
    const int t = threadIdx.x;
    const int k = blockIdx.x;
    const int start = bstart[k];
    const int end = bstart[k + 1];
    if (t < 256) lh2[t] = 0;
    __syncthreads();
    for (int i = start + t; i < end; i += 1024) {
        int e = ebuf1[i];
        atomicAdd(&lh2[dst[e] & 255], 1);
    }
    __syncthreads();
    if (t < 256) sa[t] = lh2[t];
    __syncthreads();
    int* cur = sa; int* nxt = sb;
    for (int o = 1; o < 256; o <<= 1) {
        if (t < 256) {
            int val = cur[t];
            if (t >= o) val += cur[t - o];
            nxt[t] = val;
        }
        __syncthreads();
        int* tmp = cur; cur = nxt; nxt = tmp;
    }
    if (t < 256) cur2[t] = cur[t] - lh2[t];
    __syncthreads();
    for (int i = start + t; i < end; i += 1024) {
        int e = ebuf1[i];
        int r = atomicAdd(&cur2[dst[e] & 255], 1);
        perm[start + r] = e;
    }
}

// ---------------- weight packing ----------------
// perm2: permute K rows by inv-pi so GEMM2's A-frag is register-local after
// swapped GEMM1. bias: logical row K_eff carries bias (GEMM1 fold; A has 1.0).

__global__ void pack_b_kernel(const float* __restrict__ W, const float* __restrict__ bias,
                              __bf16* __restrict__ out, int K_eff, int KS, int perm2)
{
    int idx = blockIdx.x * 256 + threadIdx.x;
    int total = KS * 8 * 64 * 8;
    if (idx >= total) return;
    int j  = idx & 7;
    int l  = (idx >> 3) & 63;
    int n  = (idx >> 9) & 7;
    int ks = idx >> 12;
    int k   = ks * 32 + ((l >> 4) << 3) + j;   // logical k'
    int col = (n << 4) + (l & 15);
    int kr = k;
    if (perm2) kr = 32 * (k >> 5) + 16 * ((k >> 2) & 1) + 4 * ((k >> 3) & 3) + (k & 3);
    float v;
    if (kr < K_eff) v = W[kr * FDIM + col];
    else if (bias && kr == K_eff) v = bias[col];
    else v = 0.0f;
    out[idx] = (__bf16)v;
}

// ---------------- MFMA node GEMM (r12-proven) ----------------

__global__ __launch_bounds__(512, 2) void node_mfma_kernel(
    const float* __restrict__ A, const __bf16* __restrict__ wp,
    const float* __restrict__ bias,
    __bf16* __restrict__ out_bf, float* __restrict__ out_f32,
    int do_swish)
{
    __shared__ __bf16 ws_[16384];   // 32 KB packed B

    const int t = threadIdx.x;
    const int l = t & 63;
    const int w = t >> 6;
    const int lrow = l & 15;
    const int kgrp = l >> 4;

    {
        const int4* g = (const int4*)wp;
        int4* s = (int4*)ws_;
        for (int i = t; i < 2048; i += 512) s[i] = g[i];
    }
    float br[8];
    #pragma unroll
    for (int n = 0; n < 8; ++n) br[n] = bias ? bias[(n << 4) + lrow] : 0.0f;
    __syncthreads();

    const int tile = blockIdx.x * 8 + w;
    if (tile >= N_ATOMS / 16) return;
    const int row0 = tile << 4;

    bf16x8 af[4];
    const float* ap = A + (size_t)(row0 + lrow) * FDIM + (kgrp << 3);
    #pragma unroll
    for (int ks = 0; ks < 4; ++ks) {
        float4 lo = *(const float4*)(ap + (ks << 5));
        float4 hi = *(const float4*)(ap + (ks << 5) + 4);
        af[ks][0] = (__bf16)lo.x; af[ks][1] = (__bf16)lo.y;
        af[ks][2] = (__bf16)lo.z; af[ks][3] = (__bf16)lo.w;
        af[ks][4] = (__bf16)hi.x; af[ks][5] = (__bf16)hi.y;
        af[ks][6] = (__bf16)hi.z; af[ks][7] = (__bf16)hi.w;
    }

    const f32x4 zero = {0.f, 0.f, 0.f, 0.f};
    f32x4 acc[8];
    #pragma unroll
    for (int n = 0; n < 8; ++n) acc[n] = zero;

    #pragma unroll
    for (int ks = 0; ks < 4; ++ks) {
        bf16x8 bfr[8];
        #pragma unroll
        for (int n = 0; n < 8; ++n)
            bfr[n] = *(const bf16x8*)((const char*)ws_ + (((ks << 3) + n) << 10) + (l << 4));
        #pragma unroll
        for (int n = 0; n < 8; ++n)
            acc[n] = __builtin_amdgcn_mfma_f32_16x16x32_bf16(af[ks], bfr[n], acc[n], 0, 0, 0);
    }

    if (out_bf) {
        #pragma unroll
        for (int r = 0; r < 4; ++r) {
            bf16x8 o;
            #pragma unroll
            for (int n = 0; n < 8; ++n) {
                float v = acc[n][r] + br[n];
                if (do_swish) v = swish_f(v);
                o[n] = (__bf16)v;
            }
            *(bf16x8*)&out_bf[(size_t)(row0 + (kgrp << 2) + r) * FDIM + (lrow << 3)] = o;
        }
    } else {
        #pragma unroll
        for (int r = 0; r < 4; ++r) {
            int orow = row0 + (kgrp << 2) + r;
            #pragma unroll
            for (int n = 0; n < 8; ++n) {
                float v = acc[n][r] + br[n];
                if (do_swish) v = swish_f(v);
                out_f32[(size_t)orow * FDIM + (n << 4) + lrow] = v;
            }
        }
    }
}

// ---------------- persistent-wave MFMA edge kernel (LDS-free H, low-pressure) ----------------
// Swapped GEMM1 interleaved with GEMM2 per ks: only 2 h-results live at a time
// (no pk[16] arrays). launch_bounds(256,2) gives the allocator room (no spill).

struct TileReg {
    float4 f0, f1;       // this lane's fij A-fragment data
    int   se_own, de_own;
    float rij_own;
};

__global__ __launch_bounds__(256, 2) void edge_kernel(
    const float* __restrict__ fij, const float* __restrict__ rij,
    const int* __restrict__ src, const int* __restrict__ dst,
    const int* __restrict__ perm,
    const __bf16* __restrict__ w1p,
    const __bf16* __restrict__ w2p, const float* __restrict__ b2,
    const __bf16* __restrict__ xb, float* __restrict__ agg)
{
    __shared__ __bf16 w2s[16384];       // 32 KB: W2 B-fragments (perm2-packed)

    const int t = threadIdx.x;
    const int l = t & 63;
    const int w = t >> 6;               // 0..3
    const int lrow = l & 15;
    const int kgrp = l >> 4;

    {
        const int4* g2 = (const int4*)w2p;
        int4* s2 = (int4*)w2s;
        for (int i = t; i < 2048; i += 256) s2[i] = g2[i];
    }

    bf16x8 w1f[8];
    float b2r[8];
    #pragma unroll
    for (int n = 0; n < 8; ++n) {
        w1f[n] = *(const bf16x8*)(w1p + (((n << 6) + l) << 3));
        b2r[n] = b2[(n << 4) + lrow];
    }
    __syncthreads();   // w2s ready; last barrier in the kernel

    const f32x4 zero = {0.f, 0.f, 0.f, 0.f};

    const int gw = blockIdx.x * 4 + w;   // global wave id
    const int NW = NBLK * 4;
    const int NT = N_EDGES / 16;
    if (gw >= NT) return;

    // fij gather; k=25 slot carries 1.0 (bias multiplier for folded b1)
    #define GATHER(T, pv) do { \
        const float* fp_ = fij + (size_t)(pv) * NB; \
        if (kgrp < 3) { \
            T.f0 = *(const float4*)(fp_ + (kgrp << 3)); \
            T.f1 = *(const float4*)(fp_ + (kgrp << 3) + 4); \
        } else { \
            T.f0 = make_float4(fp_[24], 1.0f, 0.f, 0.f); \
            T.f1 = make_float4(0.f, 0.f, 0.f, 0.f); \
        } \
        T.se_own = src[pv]; \
        T.de_own = dst[pv]; \
        T.rij_own = rij[pv]; \
    } while (0)

    TileReg cur, nxt;
    int pvB;
    {
        int pvA = perm[((size_t)gw << 4) + lrow];
        GATHER(cur, pvA);
        int i2 = gw + NW; i2 = (i2 < NT) ? i2 : (NT - 1);
        pvB = perm[((size_t)i2 << 4) + lrow];
    }

    for (int tb = gw; tb < NT; tb += NW) {
        // ---- (1) epilogue prep for CUR: shfls + xv loads FIRST (vmem head) ----
        float Cf_own = (cur.rij_own < CUTOFF_F)
                     ? 0.5f * (__cosf(cur.rij_own * PI_OVER_CUTOFF) + 1.0f) : 0.0f;
        int se4[4], de4[4]; float Cf[4];
        #pragma unroll
        for (int r = 0; r < 4; ++r) {
            se4[r] = __shfl(cur.se_own, (kgrp << 2) + r);
            Cf[r]  = __shfl(Cf_own, (kgrp << 2) + r);
            de4[r] = __shfl(cur.de_own, (kgrp << 2) + r);
        }
        bf16x8 xv4[4];
        #pragma unroll
        for (int r = 0; r < 4; ++r)
            xv4[r] = *(const bf16x8*)&xb[(size_t)se4[r] * FDIM + (lrow << 3)];

        // ---- (2) next-tile gathers AFTER xv (pad xv's vmcnt slack) ----
        GATHER(nxt, pvB);
        int i3 = tb + 2 * NW; i3 = (i3 < NT) ? i3 : (NT - 1);
        pvB = perm[((size_t)i3 << 4) + lrow];

        // ---- (3)+(4) fused per ks: GEMM1 (swapped) -> A2 concat -> GEMM2 ----
        bf16x8 a;
        a[0] = (__bf16)cur.f0.x; a[1] = (__bf16)cur.f0.y;
        a[2] = (__bf16)cur.f0.z; a[3] = (__bf16)cur.f0.w;
        a[4] = (__bf16)cur.f1.x; a[5] = (__bf16)cur.f1.y;
        a[6] = (__bf16)cur.f1.z; a[7] = (__bf16)cur.f1.w;

        f32x4 acc[8];
        #pragma unroll
        for (int n = 0; n < 8; ++n) acc[n] = zero;

        #pragma unroll
        for (int ks = 0; ks < 4; ++ks) {
            f32x4 h0 = __builtin_amdgcn_mfma_f32_16x16x32_bf16(w1f[2 * ks],     a, zero, 0, 0, 0);
            f32x4 h1 = __builtin_amdgcn_mfma_f32_16x16x32_bf16(w1f[2 * ks + 1], a, zero, 0, 0, 0);
            union { unsigned u[4]; bf16x8 v; } A2;
            A2.u[0] = ((unsigned)bfbits((__bf16)swish_f(h0[1])) << 16) | bfbits((__bf16)swish_f(h0[0]));
            A2.u[1] = ((unsigned)bfbits((__bf16)swish_f(h0[3])) << 16) | bfbits((__bf16)swish_f(h0[2]));
            A2.u[2] = ((unsigned)bfbits((__bf16)swish_f(h1[1])) << 16) | bfbits((__bf16)swish_f(h1[0]));
            A2.u[3] = ((unsigned)bfbits((__bf16)swish_f(h1[3])) << 16) | bfbits((__bf16)swish_f(h1[2]));
            bf16x8 bfr[8];
            #pragma unroll
            for (int n = 0; n < 8; ++n)
                bfr[n] = *(const bf16x8*)((const char*)w2s + (((ks << 3) + n) << 10) + (l << 4));
            #pragma unroll
            for (int n = 0; n < 8; ++n)
                acc[n] = __builtin_amdgcn_mfma_f32_16x16x32_bf16(A2.v, bfr[n], acc[n], 0, 0, 0);
        }

        // ---- (5) Epilogue: uni fast path + run-compressed atomics ----
        int d0 = __shfl(cur.de_own, 0);
        bool uni = __all(cur.de_own == d0);

        if (uni) {
            const size_t dbase = (size_t)d0 * FDIM;
            #pragma unroll
            for (int n = 0; n < 8; ++n) {
                float s = 0.f;
                #pragma unroll
                for (int r = 0; r < 4; ++r)
                    s += (float)xv4[r][n] * (acc[n][r] + b2r[n]) * Cf[r];
                s += __shfl_xor(s, 16);
                s += __shfl_xor(s, 32);
                if (kgrp == 0) unsafeAtomicAdd(&agg[dbase + (n << 4) + lrow], s);
            }
        } else {
            const bool brk0 = (de4[0] != de4[1]);
            const bool brk1 = (de4[1] != de4[2]);
            const bool brk2 = (de4[2] != de4[3]);
            #pragma unroll
            for (int n = 0; n < 8; ++n) {
                int col = (n << 4) + lrow;
                float m[4];
                #pragma unroll
                for (int r = 0; r < 4; ++r)
                    m[r] = (float)xv4[r][n] * (acc[n][r] + b2r[n]) * Cf[r];
                float run = m[0];
                if (brk0) { unsafeAtomicAdd(&agg[(size_t)de4[0] * FDIM + col], run); run = 0.f; }
                run += m[1];
                if (brk1) { unsafeAtomicAdd(&agg[(size_t)de4[1] * FDIM + col], run); run = 0.f; }
                run += m[2];
                if (brk2) { unsafeAtomicAdd(&agg[(size_t)de4[2] * FDIM + col], run); run = 0.f; }
                run += m[3];
                unsafeAtomicAdd(&agg[(size_t)de4[3] * FDIM + col], run);
            }
        }

        cur = nxt;
    }
    #undef GATHER
}

extern "C" void kernel_launch(void* const* d_in, const int* in_sizes, int n_in,
                              void* d_out, int out_size, void* d_ws, size_t ws_size,
                              hipStream_t stream)
{
    const float* feat   = (const float*)d_in[0];
    const float* fij    = (const float*)d_in[1];
    const float* rij    = (const float*)d_in[2];
    const int*   src    = (const int*)d_in[3];
    const int*   dst    = (const int*)d_in[4];
    const float* W_in2f = (const float*)d_in[5];
    const float* W_f1   = (const float*)d_in[6];
    const float* b_f1   = (const float*)d_in[7];
    const float* W_f2   = (const float*)d_in[8];
    const float* b_f2   = (const float*)d_in[9];
    const float* W_out  = (const float*)d_in[10];
    const float* b_out  = (const float*)d_in[11];
    float* out = (float*)d_out;

    // ws layout, total 33,333,696 B (r18-proven)
    char* ws = (char*)d_ws;
    __bf16* xb    = (__bf16*)ws;                  // 12,800,000 B
    __bf16* w1p   = (__bf16*)(ws + 12800000);     //      8,192 B
    __bf16* w2p   = (__bf16*)(ws + 12808192);     //     32,768 B
    __bf16* winp  = (__bf16*)(ws + 12840960);     //     32,768 B
    __bf16* woutp = (__bf16*)(ws + 12873728);     //     32,768 B
    int*    bt    = (int*)(ws + 12906496);        //      1,024 B
    int*    gh    = (int*)(ws + 12907520);        //    613,088 B
    int*    off   = (int*)(ws + 13520608);        //    613,088 B
    int*    ebkt  = (int*)(ws + 14133696);        //  6,400,000 B
    int*    ebuf1 = (int*)(ws + 20533696);        //  6,400,000 B
    int*    perm  = (int*)(ws + 26933696);        //  6,400,000 B
    float*  agg   = out;                          // accumulate into d_out

    hipMemsetAsync(agg, 0, (size_t)N_ATOMS * FDIM * sizeof(float), stream);

    // LDS-radix group-by-dst (no global atomics)
    radix1_hist_kernel<<<P1B, 256, 0, stream>>>(dst, ebkt, gh);
    scan_buckets_kernel<<<RB, 256, 0, stream>>>(gh, off, bt);
    scan_base_kernel<<<1, 256, 0, stream>>>(bt);
    radix1_place_kernel<<<P1B, 256, 0, stream>>>(ebkt, off, bt, ebuf1);
    radix2_kernel<<<RB, 1024, 0, stream>>>(ebuf1, dst, bt, perm);

    // W1: bias folded at logical row 25; W2: rows permuted by inv-pi
    pack_b_kernel<<<(4096 + 255) / 256, 256, 0, stream>>>(W_f1, b_f1, w1p, NB, 1, 0);
    pack_b_kernel<<<(16384 + 255) / 256, 256, 0, stream>>>(W_f2, nullptr, w2p, 128, 4, 1);
    pack_b_kernel<<<(16384 + 255) / 256, 256, 0, stream>>>(W_in2f, nullptr, winp, 128, 4, 0);
    pack_b_kernel<<<(16384 + 255) / 256, 256, 0, stream>>>(W_out, nullptr, woutp, 128, 4, 0);

    // x = feat @ W_in2f  -> xb (bf16, permuted)
    node_mfma_kernel<<<(N_ATOMS / 16 + 7) / 8, 512, 0, stream>>>(
        feat, winp, nullptr, xb, nullptr, 0);

    edge_kernel<<<NBLK, 256, 0, stream>>>(
        fij, rij, src, dst, perm, w1p, w2p, b_f2, xb, agg);

    // out = swish(agg @ W_out + b_out)  (in-place per 16-row tile)
    node_mfma_kernel<<<(N_ATOMS / 16 + 7) / 8, 512, 0, stream>>>(
        agg, woutp, b_out, nullptr, out, 1);
}

// Round 21
// 449.813 us; speedup vs baseline: 2.0774x; 1.1945x over previous
//
#include <hip/hip_runtime.h>
#include <hip/hip_bf16.h>
#include <math.h>

#define N_ATOMS 50000
#define N_EDGES 1600000
#define FDIM 128
#define NB 25
#define CUTOFF_F 5.0f
#define PI_OVER_CUTOFF 0.6283185307179586f
#define NBLK 512  // persistent blocks for edge kernel
#define RB 196    // radix buckets = dst>>8 (50000>>8 -> 0..195)
#define P1B 782   // pass-1 blocks = ceil(1.6M / 2048)

typedef __bf16 bf16x8 __attribute__((ext_vector_type(8)));
typedef float f32x4 __attribute__((ext_vector_type(4)));

__device__ __forceinline__ float swish_f(float v) {
    // v * rcp(1+e^-v): v_rcp_f32 (~1ulp) instead of full-precision divide
    return v * __builtin_amdgcn_rcpf(1.0f + __expf(-v));
}

// XOR swizzle on 16B slots (for 256B-stride hs rows).
#define SWZ(row) ((((row) & 7) ^ (((row) >> 3) & 1)) << 4)

// ---------------- LDS-radix group-by-dst (zero global atomics) ----------------

__global__ __launch_bounds__(256) void radix1_hist_kernel(
    const int* __restrict__ dst, int* __restrict__ ebkt, int* __restrict__ gh)
{
    __shared__ int lh[RB];
    const int t = threadIdx.x;
    const int b = blockIdx.x;
    for (int i = t; i < RB; i += 256) lh[i] = 0;
    __syncthreads();
    const int base = b * 2048;
    #pragma unroll
    for (int it = 0; it < 8; ++it) {
        int i = base + it * 256 + t;
        if (i < N_EDGES) {
            int bkt = dst[i] >> 8;
            int rank = atomicAdd(&lh[bkt], 1);   // LDS atomic
            ebkt[i] = (bkt << 11) | rank;        // rank <= 2047 fits 11 bits
        }
    }
    __syncthreads();
    for (int i = t; i < RB; i += 256) gh[i * P1B + b] = lh[i];
}

__global__ __launch_bounds__(256) void scan_buckets_kernel(
    const int* __restrict__ gh, int* __restrict__ off, int* __restrict__ bt)
{
    __shared__ int sa[256], sb[256];
    const int k = blockIdx.x;
    const int t = threadIdx.x;
    const int base = k * P1B;
    int v[4]; int s = 0;
    #pragma unroll
    for (int j = 0; j < 4; ++j) {
        int b = t * 4 + j;
        v[j] = (b < P1B) ? gh[base + b] : 0;
        s += v[j];
    }
    sa[t] = s;
    __syncthreads();
    int* cur = sa; int* nxt = sb;
    for (int o = 1; o < 256; o <<= 1) {
        int val = cur[t];
        if (t >= o) val += cur[t - o];
        nxt[t] = val;
        __syncthreads();
        int* tmp = cur; cur = nxt; nxt = tmp;
    }
    int run = cur[t] - s;                 // exclusive prefix for this thread
    #pragma unroll
    for (int j = 0; j < 4; ++j) {
        int b = t * 4 + j;
        if (b < P1B) off[base + b] = run;
        run += v[j];
    }
    if (t == 255) bt[k] = cur[t];         // bucket total
}

__global__ __launch_bounds__(256) void scan_base_kernel(int* __restrict__ bt) {
    __shared__ int sa[256], sb[256];
    const int t = threadIdx.x;
    int v = (t < RB) ? bt[t] : 0;
    sa[t] = v;
    __syncthreads();
    int* cur = sa; int* nxt = sb;
    for (int o = 1; o < 256; o <<= 1) {
        int val = cur[t];
        if (t >= o) val += cur[t - o];
        nxt[t] = val;
        __syncthreads();
        int* tmp = cur; cur = nxt; nxt = tmp;
    }
    if (t < RB) bt[t] = cur[t] - v;       // exclusive
    if (t == RB - 1) bt[RB] = cur[t];     // total = N_EDGES
}

__global__ __launch_bounds__(256) void radix1_place_kernel(
    const int* __restrict__ ebkt, const int* __restrict__ off,
    const int* __restrict__ bstart, int* __restrict__ ebuf1)
{
    __shared__ int obs[RB];
    const int t = threadIdx.x;
    const int b = blockIdx.x;
    if (t < RB) obs[t] = bstart[t] + off[t * P1B + b];
    __syncthreads();
    const int base = b * 2048;
    #pragma unroll
    for (int it = 0; it < 8; ++it) {
        int i = base + it * 256 + t;
        if (i < N_EDGES) {
            int p = ebkt[i];
            ebuf1[obs[p >> 11] + (p & 2047)] = i;
        }
    }
}

__global__ __launch_bounds__(1024) void radix2_kernel(
    const int* __restrict__ ebuf1, const int* __restrict__ dst,
    const int* __restrict__ bstart, int* __restrict__ perm)
{
    __shared__ int lh2[256], sa[256], sb[256], cur2[256];
    const int t = threadIdx.x;
    const int k = blockIdx.x;
    const int start = bstart[k];
    const int end = bstart[k + 1];
    if (t < 256) lh2[t] = 0;
    __syncthreads();
    for (int i = start + t; i < end; i += 1024) {
        int e = ebuf1[i];
        atomicAdd(&lh2[dst[e] & 255], 1);   // LDS atomic
    }
    __syncthreads();
    if (t < 256) sa[t] = lh2[t];
    __syncthreads();
    int* cur = sa; int* nxt = sb;
    for (int o = 1; o < 256; o <<= 1) {
        if (t < 256) {
            int val = cur[t];
            if (t >= o) val += cur[t - o];
            nxt[t] = val;
        }
        __syncthreads();
        int* tmp = cur; cur = nxt; nxt = tmp;
    }
    if (t < 256) cur2[t] = cur[t] - lh2[t];   // exclusive bin start
    __syncthreads();
    for (int i = start + t; i < end; i += 1024) {
        int e = ebuf1[i];
        int r = atomicAdd(&cur2[dst[e] & 255], 1);   // LDS cursor
        perm[start + r] = e;
    }
}

// ---------------- weight packing ----------------

__global__ void pack_b_kernel(const float* __restrict__ W, __bf16* __restrict__ out,
                              int K_eff, int KS)
{
    int idx = blockIdx.x * 256 + threadIdx.x;
    int total = KS * 8 * 64 * 8;
    if (idx >= total) return;
    int j  = idx & 7;
    int l  = (idx >> 3) & 63;
    int n  = (idx >> 9) & 7;
    int ks = idx >> 12;
    int k   = ks * 32 + ((l >> 4) << 3) + j;
    int col = (n << 4) + (l & 15);
    float v = (k < K_eff) ? W[k * FDIM + col] : 0.0f;
    out[idx] = (__bf16)v;
}

// ---------------- MFMA node GEMM (r12-proven) ----------------

__global__ __launch_bounds__(512, 2) void node_mfma_kernel(
    const float* __restrict__ A, const __bf16* __restrict__ wp,
    const float* __restrict__ bias,
    __bf16* __restrict__ out_bf, float* __restrict__ out_f32,
    int do_swish)
{
    __shared__ __bf16 ws_[16384];   // 32 KB packed B

    const int t = threadIdx.x;
    const int l = t & 63;
    const int w = t >> 6;
    const int lrow = l & 15;
    const int kgrp = l >> 4;

    {
        const int4* g = (const int4*)wp;
        int4* s = (int4*)ws_;
        for (int i = t; i < 2048; i += 512) s[i] = g[i];
    }
    float br[8];
    #pragma unroll
    for (int n = 0; n < 8; ++n) br[n] = bias ? bias[(n << 4) + lrow] : 0.0f;
    __syncthreads();

    const int tile = blockIdx.x * 8 + w;
    if (tile >= N_ATOMS / 16) return;
    const int row0 = tile << 4;

    bf16x8 af[4];
    const float* ap = A + (size_t)(row0 + lrow) * FDIM + (kgrp << 3);
    #pragma unroll
    for (int ks = 0; ks < 4; ++ks) {
        float4 lo = *(const float4*)(ap + (ks << 5));
        float4 hi = *(const float4*)(ap + (ks << 5) + 4);
        af[ks][0] = (__bf16)lo.x; af[ks][1] = (__bf16)lo.y;
        af[ks][2] = (__bf16)lo.z; af[ks][3] = (__bf16)lo.w;
        af[ks][4] = (__bf16)hi.x; af[ks][5] = (__bf16)hi.y;
        af[ks][6] = (__bf16)hi.z; af[ks][7] = (__bf16)hi.w;
    }

    const f32x4 zero = {0.f, 0.f, 0.f, 0.f};
    f32x4 acc[8];
    #pragma unroll
    for (int n = 0; n < 8; ++n) acc[n] = zero;

    #pragma unroll
    for (int ks = 0; ks < 4; ++ks) {
        bf16x8 bfr[8];
        #pragma unroll
        for (int n = 0; n < 8; ++n)
            bfr[n] = *(const bf16x8*)((const char*)ws_ + (((ks << 3) + n) << 10) + (l << 4));
        #pragma unroll
        for (int n = 0; n < 8; ++n)
            acc[n] = __builtin_amdgcn_mfma_f32_16x16x32_bf16(af[ks], bfr[n], acc[n], 0, 0, 0);
    }

    if (out_bf) {
        #pragma unroll
        for (int r = 0; r < 4; ++r) {
            bf16x8 o;
            #pragma unroll
            for (int n = 0; n < 8; ++n) {
                float v = acc[n][r] + br[n];
                if (do_swish) v = swish_f(v);
                o[n] = (__bf16)v;
            }
            *(bf16x8*)&out_bf[(size_t)(row0 + (kgrp << 2) + r) * FDIM + (lrow << 3)] = o;
        }
    } else {
        #pragma unroll
        for (int r = 0; r < 4; ++r) {
            int orow = row0 + (kgrp << 2) + r;
            #pragma unroll
            for (int n = 0; n < 8; ++n) {
                float v = acc[n][r] + br[n];
                if (do_swish) v = swish_f(v);
                out_f32[(size_t)orow * FDIM + (n << 4) + lrow] = v;
            }
        }
    }
}

// ---------------- persistent-wave MFMA edge kernel (r17/r18 structure) ----------------
// xv loads are the FIRST vmem ops of each iteration (vmcnt FIFO: epilogue's
// xv wait never drains the previous iteration's atomics).

struct TileReg {
    float4 f0, f1;       // this lane's fij A-fragment data
    int   se_own, de_own;
    float rij_own;
};

__global__ __launch_bounds__(512, 2) void edge_kernel(
    const float* __restrict__ fij, const float* __restrict__ rij,
    const int* __restrict__ src, const int* __restrict__ dst,
    const int* __restrict__ perm,
    const __bf16* __restrict__ w1p, const float* __restrict__ b1,
    const __bf16* __restrict__ w2p, const float* __restrict__ b2,
    const __bf16* __restrict__ xb, float* __restrict__ agg)
{
    __shared__ __bf16 w2s[16384];       // 32 KB: W2 B-fragments
    __shared__ __bf16 hs[8][16 * 128];  // 32 KB: per-wave H tiles

    const int t = threadIdx.x;
    const int l = t & 63;
    const int w = t >> 6;               // 0..7
    const int lrow = l & 15;
    const int kgrp = l >> 4;

    {
        const int4* g2 = (const int4*)w2p;
        int4* s2 = (int4*)w2s;
        for (int i = t; i < 2048; i += 512) s2[i] = g2[i];
    }

    bf16x8 w1f[8];
    float b1r[8], b2r[8];
    #pragma unroll
    for (int n = 0; n < 8; ++n) {
        w1f[n] = *(const bf16x8*)(w1p + (((n << 6) + l) << 3));
        b1r[n] = b1[(n << 4) + lrow];
        b2r[n] = b2[(n << 4) + lrow];
    }
    __syncthreads();   // w2s ready; last barrier in the kernel

    __bf16* hw = hs[w];
    const f32x4 zero = {0.f, 0.f, 0.f, 0.f};

    const int gw = blockIdx.x * 8 + w;   // global wave id
    const int NW = NBLK * 8;
    const int NT = N_EDGES / 16;
    if (gw >= NT) return;

    #define GATHER(T, pv) do { \
        const float* fp_ = fij + (size_t)(pv) * NB; \
        if (kgrp < 3) { \
            T.f0 = *(const float4*)(fp_ + (kgrp << 3)); \
            T.f1 = *(const float4*)(fp_ + (kgrp << 3) + 4); \
        } else { \
            T.f0 = make_float4(fp_[24], 0.f, 0.f, 0.f); \
            T.f1 = make_float4(0.f, 0.f, 0.f, 0.f); \
        } \
        T.se_own = src[pv]; \
        T.de_own = dst[pv]; \
        T.rij_own = rij[pv]; \
    } while (0)

    TileReg cur, nxt;
    int pvB;
    {
        int pvA = perm[((size_t)gw << 4) + lrow];
        GATHER(cur, pvA);
        int i2 = gw + NW; i2 = (i2 < NT) ? i2 : (NT - 1);
        pvB = perm[((size_t)i2 << 4) + lrow];
    }

    for (int tb = gw; tb < NT; tb += NW) {
        // ---- (1) epilogue prep for CUR: shfls + xv loads FIRST (vmem head) ----
        float Cf_own = (cur.rij_own < CUTOFF_F)
                     ? 0.5f * (__cosf(cur.rij_own * PI_OVER_CUTOFF) + 1.0f) : 0.0f;
        int se4[4], de4[4]; float Cf[4];
        #pragma unroll
        for (int r = 0; r < 4; ++r) {
            se4[r] = __shfl(cur.se_own, (kgrp << 2) + r);
            Cf[r]  = __shfl(Cf_own, (kgrp << 2) + r);
            de4[r] = __shfl(cur.de_own, (kgrp << 2) + r);
        }
        bf16x8 xv4[4];
        #pragma unroll
        for (int r = 0; r < 4; ++r)
            xv4[r] = *(const bf16x8*)&xb[(size_t)se4[r] * FDIM + (lrow << 3)];

        // ---- (2) next-tile gathers AFTER xv (these pad xv's vmcnt slack) ----
        GATHER(nxt, pvB);
        int i3 = tb + 2 * NW; i3 = (i3 < NT) ? i3 : (NT - 1);
        pvB = perm[((size_t)i3 << 4) + lrow];

        // ---- (3) GEMM1: H = swish(fij_pad @ W1 + b1) -> hw (wave-local) ----
        bf16x8 a;
        a[0] = (__bf16)cur.f0.x; a[1] = (__bf16)cur.f0.y;
        a[2] = (__bf16)cur.f0.z; a[3] = (__bf16)cur.f0.w;
        a[4] = (__bf16)cur.f1.x; a[5] = (__bf16)cur.f1.y;
        a[6] = (__bf16)cur.f1.z; a[7] = (__bf16)cur.f1.w;

        #pragma unroll
        for (int n = 0; n < 8; ++n) {
            f32x4 h = __builtin_amdgcn_mfma_f32_16x16x32_bf16(a, w1f[n], zero, 0, 0, 0);
            #pragma unroll
            for (int r = 0; r < 4; ++r) {
                int hrow = (kgrp << 2) + r;
                float hv = swish_f(h[r] + b1r[n]);
                int byte = (hrow << 8) + (((n << 4) + lrow) << 1);
                byte ^= SWZ(hrow);
                *(__bf16*)((char*)hw + byte) = (__bf16)hv;
            }
        }
        // no barrier: hw is wave-local (same-wave DS ops are ordered)

        // ---- (4) GEMM2: Wfilt = H @ W2 (B-frags batched from LDS) ----
        f32x4 acc[8];
        #pragma unroll
        for (int n = 0; n < 8; ++n) acc[n] = zero;

        #pragma unroll
        for (int ks = 0; ks < 4; ++ks) {
            int byte = (lrow << 8) + (ks << 6) + (kgrp << 4);
            byte ^= SWZ(lrow);
            bf16x8 a2 = *(const bf16x8*)((const char*)hw + byte);
            bf16x8 bfr[8];
            #pragma unroll
            for (int n = 0; n < 8; ++n)
                bfr[n] = *(const bf16x8*)((const char*)w2s + (((ks << 3) + n) << 10) + (l << 4));
            #pragma unroll
            for (int n = 0; n < 8; ++n)
                acc[n] = __builtin_amdgcn_mfma_f32_16x16x32_bf16(a2, bfr[n], acc[n], 0, 0, 0);
        }

        // ---- (5) Epilogue: uni fast path + run-compressed atomics ----
        int d0 = __shfl(cur.de_own, 0);
        bool uni = __all(cur.de_own == d0);

        if (uni) {
            const size_t dbase = (size_t)d0 * FDIM;
            #pragma unroll
            for (int n = 0; n < 8; ++n) {
                float s = 0.f;
                #pragma unroll
                for (int r = 0; r < 4; ++r)
                    s += (float)xv4[r][n] * (acc[n][r] + b2r[n]) * Cf[r];
                s += __shfl_xor(s, 16);
                s += __shfl_xor(s, 32);
                if (kgrp == 0) unsafeAtomicAdd(&agg[dbase + (n << 4) + lrow], s);
            }
        } else {
            const bool brk0 = (de4[0] != de4[1]);
            const bool brk1 = (de4[1] != de4[2]);
            const bool brk2 = (de4[2] != de4[3]);
            #pragma unroll
            for (int n = 0; n < 8; ++n) {
                int col = (n << 4) + lrow;
                float m[4];
                #pragma unroll
                for (int r = 0; r < 4; ++r)
                    m[r] = (float)xv4[r][n] * (acc[n][r] + b2r[n]) * Cf[r];
                float run = m[0];
                if (brk0) { unsafeAtomicAdd(&agg[(size_t)de4[0] * FDIM + col], run); run = 0.f; }
                run += m[1];
                if (brk1) { unsafeAtomicAdd(&agg[(size_t)de4[1] * FDIM + col], run); run = 0.f; }
                run += m[2];
                if (brk2) { unsafeAtomicAdd(&agg[(size_t)de4[2] * FDIM + col], run); run = 0.f; }
                run += m[3];
                unsafeAtomicAdd(&agg[(size_t)de4[3] * FDIM + col], run);
            }
        }

        cur = nxt;
    }
    #undef GATHER
}

extern "C" void kernel_launch(void* const* d_in, const int* in_sizes, int n_in,
                              void* d_out, int out_size, void* d_ws, size_t ws_size,
                              hipStream_t stream)
{
    const float* feat   = (const float*)d_in[0];
    const float* fij    = (const float*)d_in[1];
    const float* rij    = (const float*)d_in[2];
    const int*   src    = (const int*)d_in[3];
    const int*   dst    = (const int*)d_in[4];
    const float* W_in2f = (const float*)d_in[5];
    const float* W_f1   = (const float*)d_in[6];
    const float* b_f1   = (const float*)d_in[7];
    const float* W_f2   = (const float*)d_in[8];
    const float* b_f2   = (const float*)d_in[9];
    const float* W_out  = (const float*)d_in[10];
    const float* b_out  = (const float*)d_in[11];
    float* out = (float*)d_out;

    // ws layout, total 33,333,696 B (r18-proven)
    char* ws = (char*)d_ws;
    __bf16* xb    = (__bf16*)ws;                  // 12,800,000 B
    __bf16* w1p   = (__bf16*)(ws + 12800000);     //      8,192 B
    __bf16* w2p   = (__bf16*)(ws + 12808192);     //     32,768 B
    __bf16* winp  = (__bf16*)(ws + 12840960);     //     32,768 B
    __bf16* woutp = (__bf16*)(ws + 12873728);     //     32,768 B
    int*    bt    = (int*)(ws + 12906496);        //      1,024 B (197 ints)
    int*    gh    = (int*)(ws + 12907520);        //    613,088 B
    int*    off   = (int*)(ws + 13520608);        //    613,088 B
    int*    ebkt  = (int*)(ws + 14133696);        //  6,400,000 B
    int*    ebuf1 = (int*)(ws + 20533696);        //  6,400,000 B
    int*    perm  = (int*)(ws + 26933696);        //  6,400,000 B
    float*  agg   = out;                          // accumulate into d_out

    hipMemsetAsync(agg, 0, (size_t)N_ATOMS * FDIM * sizeof(float), stream);

    // LDS-radix group-by-dst (no global atomics)
    radix1_hist_kernel<<<P1B, 256, 0, stream>>>(dst, ebkt, gh);
    scan_buckets_kernel<<<RB, 256, 0, stream>>>(gh, off, bt);
    scan_base_kernel<<<1, 256, 0, stream>>>(bt);
    radix1_place_kernel<<<P1B, 256, 0, stream>>>(ebkt, off, bt, ebuf1);
    radix2_kernel<<<RB, 1024, 0, stream>>>(ebuf1, dst, bt, perm);

    pack_b_kernel<<<(4096 + 255) / 256, 256, 0, stream>>>(W_f1, w1p, NB, 1);
    pack_b_kernel<<<(16384 + 255) / 256, 256, 0, stream>>>(W_f2, w2p, 128, 4);
    pack_b_kernel<<<(16384 + 255) / 256, 256, 0, stream>>>(W_in2f, winp, 128, 4);
    pack_b_kernel<<<(16384 + 255) / 256, 256, 0, stream>>>(W_out, woutp, 128, 4);

    // x = feat @ W_in2f  -> xb (bf16, permuted)
    node_mfma_kernel<<<(N_ATOMS / 16 + 7) / 8, 512, 0, stream>>>(
        feat, winp, nullptr, xb, nullptr, 0);

    edge_kernel<<<NBLK, 512, 0, stream>>>(
        fij, rij, src, dst, perm, w1p, b_f1, w2p, b_f2, xb, agg);

    // out = swish(agg @ W_out + b_out)  (in-place per 16-row tile)
    node_mfma_kernel<<<(N_ATOMS / 16 + 7) / 8, 512, 0, stream>>>(
        agg, woutp, b_out, nullptr, out, 1);
}

// Round 22
// 449.150 us; speedup vs baseline: 2.0805x; 1.0015x over previous
//
#include <hip/hip_runtime.h>
#include <hip/hip_bf16.h>
#include <math.h>

#define N_ATOMS 50000
#define N_EDGES 1600000
#define FDIM 128
#define NB 25
#define CUTOFF_F 5.0f
#define PI_OVER_CUTOFF 0.6283185307179586f
#define NBLK 512  // persistent blocks for edge kernel
#define RB 196    // radix buckets = dst>>8 (50000>>8 -> 0..195)
#define P1B 782   // pass-1 blocks = ceil(1.6M / 2048)

typedef __bf16 bf16x8 __attribute__((ext_vector_type(8)));
typedef float f32x4 __attribute__((ext_vector_type(4)));

__device__ __forceinline__ float swish_f(float v) {
    // v * rcp(1+e^-v): v_rcp_f32 (~1ulp) instead of full-precision divide
    return v * __builtin_amdgcn_rcpf(1.0f + __expf(-v));
}

// XOR swizzle on 16B slots (for 256B-stride hs rows).
#define SWZ(row) ((((row) & 7) ^ (((row) >> 3) & 1)) << 4)

// ---------------- LDS-radix group-by-dst (zero global atomics) ----------------

__global__ __launch_bounds__(256) void radix1_hist_kernel(
    const int* __restrict__ dst, int* __restrict__ ebkt, int* __restrict__ gh)
{
    __shared__ int lh[RB];
    const int t = threadIdx.x;
    const int b = blockIdx.x;
    for (int i = t; i < RB; i += 256) lh[i] = 0;
    __syncthreads();
    const int base = b * 2048;
    #pragma unroll
    for (int it = 0; it < 8; ++it) {
        int i = base + it * 256 + t;
        if (i < N_EDGES) {
            int bkt = dst[i] >> 8;
            int rank = atomicAdd(&lh[bkt], 1);   // LDS atomic
            ebkt[i] = (bkt << 11) | rank;        // rank <= 2047 fits 11 bits
        }
    }
    __syncthreads();
    for (int i = t; i < RB; i += 256) gh[i * P1B + b] = lh[i];
}

__global__ __launch_bounds__(256) void scan_buckets_kernel(
    const int* __restrict__ gh, int* __restrict__ off, int* __restrict__ bt)
{
    __shared__ int sa[256], sb[256];
    const int k = blockIdx.x;
    const int t = threadIdx.x;
    const int base = k * P1B;
    int v[4]; int s = 0;
    #pragma unroll
    for (int j = 0; j < 4; ++j) {
        int b = t * 4 + j;
        v[j] = (b < P1B) ? gh[base + b] : 0;
        s += v[j];
    }
    sa[t] = s;
    __syncthreads();
    int* cur = sa; int* nxt = sb;
    for (int o = 1; o < 256; o <<= 1) {
        int val = cur[t];
        if (t >= o) val += cur[t - o];
        nxt[t] = val;
        __syncthreads();
        int* tmp = cur; cur = nxt; nxt = tmp;
    }
    int run = cur[t] - s;                 // exclusive prefix for this thread
    #pragma unroll
    for (int j = 0; j < 4; ++j) {
        int b = t * 4 + j;
        if (b < P1B) off[base + b] = run;
        run += v[j];
    }
    if (t == 255) bt[k] = cur[t];         // bucket total
}

__global__ __launch_bounds__(256) void scan_base_kernel(int* __restrict__ bt) {
    __shared__ int sa[256], sb[256];
    const int t = threadIdx.x;
    int v = (t < RB) ? bt[t] : 0;
    sa[t] = v;
    __syncthreads();
    int* cur = sa; int* nxt = sb;
    for (int o = 1; o < 256; o <<= 1) {
        int val = cur[t];
        if (t >= o) val += cur[t - o];
        nxt[t] = val;
        __syncthreads();
        int* tmp = cur; cur = nxt; nxt = tmp;
    }
    if (t < RB) bt[t] = cur[t] - v;       // exclusive
    if (t == RB - 1) bt[RB] = cur[t];     // total = N_EDGES
}

__global__ __launch_bounds__(256) void radix1_place_kernel(
    const int* __restrict__ ebkt, const int* __restrict__ off,
    const int* __restrict__ bstart, int* __restrict__ ebuf1)
{
    __shared__ int obs[RB];
    const int t = threadIdx.x;
    const int b = blockIdx.x;
    if (t < RB) obs[t] = bstart[t] + off[t * P1B + b];
    __syncthreads();
    const int base = b * 2048;
    #pragma unroll
    for (int it = 0; it < 8; ++it) {
        int i = base + it * 256 + t;
        if (i < N_EDGES) {
            int p = ebkt[i];
            ebuf1[obs[p >> 11] + (p & 2047)] = i;
        }
    }
}

__global__ __launch_bounds__(1024) void radix2_kernel(
    const int* __restrict__ ebuf1, const int* __restrict__ dst,
    const int* __restrict__ bstart, int* __restrict__ perm)
{
    __shared__ int lh2[256], sa[256], sb[256], cur2[256];
    const int t = threadIdx.x;
    const int k = blockIdx.x;
    const int start = bstart[k];
    const int end = bstart[k + 1];
    if (t < 256) lh2[t] = 0;
    __syncthreads();
    for (int i = start + t; i < end; i += 1024) {
        int e = ebuf1[i];
        atomicAdd(&lh2[dst[e] & 255], 1);   // LDS atomic
    }
    __syncthreads();
    if (t < 256) sa[t] = lh2[t];
    __syncthreads();
    int* cur = sa; int* nxt = sb;
    for (int o = 1; o < 256; o <<= 1) {
        if (t < 256) {
            int val = cur[t];
            if (t >= o) val += cur[t - o];
            nxt[t] = val;
        }
        __syncthreads();
        int* tmp = cur; cur = nxt; nxt = tmp;
    }
    if (t < 256) cur2[t] = cur[t] - lh2[t];   // exclusive bin start
    __syncthreads();
    for (int i = start + t; i < end; i += 1024) {
        int e = ebuf1[i];
        int r = atomicAdd(&cur2[dst[e] & 255], 1);   // LDS cursor
        perm[start + r] = e;
    }
}

// ---------------- weight packing ----------------

__global__ void pack_b_kernel(const float* __restrict__ W, __bf16* __restrict__ out,
                              int K_eff, int KS)
{
    int idx = blockIdx.x * 256 + threadIdx.x;
    int total = KS * 8 * 64 * 8;
    if (idx >= total) return;
    int j  = idx & 7;
    int l  = (idx >> 3) & 63;
    int n  = (idx >> 9) & 7;
    int ks = idx >> 12;
    int k   = ks * 32 + ((l >> 4) << 3) + j;
    int col = (n << 4) + (l & 15);
    float v = (k < K_eff) ? W[k * FDIM + col] : 0.0f;
    out[idx] = (__bf16)v;
}

// ---------------- MFMA node GEMM (r12-proven) ----------------

__global__ __launch_bounds__(512, 2) void node_mfma_kernel(
    const float* __restrict__ A, const __bf16* __restrict__ wp,
    const float* __restrict__ bias,
    __bf16* __restrict__ out_bf, float* __restrict__ out_f32,
    int do_swish)
{
    __shared__ __bf16 ws_[16384];   // 32 KB packed B

    const int t = threadIdx.x;
    const int l = t & 63;
    const int w = t >> 6;
    const int lrow = l & 15;
    const int kgrp = l >> 4;

    {
        const int4* g = (const int4*)wp;
        int4* s = (int4*)ws_;
        for (int i = t; i < 2048; i += 512) s[i] = g[i];
    }
    float br[8];
    #pragma unroll
    for (int n = 0; n < 8; ++n) br[n] = bias ? bias[(n << 4) + lrow] : 0.0f;
    __syncthreads();

    const int tile = blockIdx.x * 8 + w;
    if (tile >= N_ATOMS / 16) return;
    const int row0 = tile << 4;

    bf16x8 af[4];
    const float* ap = A + (size_t)(row0 + lrow) * FDIM + (kgrp << 3);
    #pragma unroll
    for (int ks = 0; ks < 4; ++ks) {
        float4 lo = *(const float4*)(ap + (ks << 5));
        float4 hi = *(const float4*)(ap + (ks << 5) + 4);
        af[ks][0] = (__bf16)lo.x; af[ks][1] = (__bf16)lo.y;
        af[ks][2] = (__bf16)lo.z; af[ks][3] = (__bf16)lo.w;
        af[ks][4] = (__bf16)hi.x; af[ks][5] = (__bf16)hi.y;
        af[ks][6] = (__bf16)hi.z; af[ks][7] = (__bf16)hi.w;
    }

    const f32x4 zero = {0.f, 0.f, 0.f, 0.f};
    f32x4 acc[8];
    #pragma unroll
    for (int n = 0; n < 8; ++n) acc[n] = zero;

    #pragma unroll
    for (int ks = 0; ks < 4; ++ks) {
        bf16x8 bfr[8];
        #pragma unroll
        for (int n = 0; n < 8; ++n)
            bfr[n] = *(const bf16x8*)((const char*)ws_ + (((ks << 3) + n) << 10) + (l << 4));
        #pragma unroll
        for (int n = 0; n < 8; ++n)
            acc[n] = __builtin_amdgcn_mfma_f32_16x16x32_bf16(af[ks], bfr[n], acc[n], 0, 0, 0);
    }

    if (out_bf) {
        #pragma unroll
        for (int r = 0; r < 4; ++r) {
            bf16x8 o;
            #pragma unroll
            for (int n = 0; n < 8; ++n) {
                float v = acc[n][r] + br[n];
                if (do_swish) v = swish_f(v);
                o[n] = (__bf16)v;
            }
            *(bf16x8*)&out_bf[(size_t)(row0 + (kgrp << 2) + r) * FDIM + (lrow << 3)] = o;
        }
    } else {
        #pragma unroll
        for (int r = 0; r < 4; ++r) {
            int orow = row0 + (kgrp << 2) + r;
            #pragma unroll
            for (int n = 0; n < 8; ++n) {
                float v = acc[n][r] + br[n];
                if (do_swish) v = swish_f(v);
                out_f32[(size_t)orow * FDIM + (n << 4) + lrow] = v;
            }
        }
    }
}

// ---------------- persistent-wave MFMA edge kernel ----------------
// Contiguous chunk per wave (25 tiles) + cross-tile accumulator carry:
// consecutive tiles usually share the dst run (avg run = 32 edges = 2 tiles),
// so uni windows accumulate in registers and flush once per run. xv loads
// remain the first vmem ops of each iteration (r17-proven ordering).

struct TileReg {
    float4 f0, f1;       // this lane's fij A-fragment data
    int   se_own, de_own;
    float rij_own;
};

__global__ __launch_bounds__(512, 2) void edge_kernel(
    const float* __restrict__ fij, const float* __restrict__ rij,
    const int* __restrict__ src, const int* __restrict__ dst,
    const int* __restrict__ perm,
    const __bf16* __restrict__ w1p, const float* __restrict__ b1,
    const __bf16* __restrict__ w2p, const float* __restrict__ b2,
    const __bf16* __restrict__ xb, float* __restrict__ agg)
{
    __shared__ __bf16 w2s[16384];       // 32 KB: W2 B-fragments
    __shared__ __bf16 hs[8][16 * 128];  // 32 KB: per-wave H tiles

    const int t = threadIdx.x;
    const int l = t & 63;
    const int w = t >> 6;               // 0..7
    const int lrow = l & 15;
    const int kgrp = l >> 4;

    {
        const int4* g2 = (const int4*)w2p;
        int4* s2 = (int4*)w2s;
        for (int i = t; i < 2048; i += 512) s2[i] = g2[i];
    }

    bf16x8 w1f[8];
    float b1r[8], b2r[8];
    #pragma unroll
    for (int n = 0; n < 8; ++n) {
        w1f[n] = *(const bf16x8*)(w1p + (((n << 6) + l) << 3));
        b1r[n] = b1[(n << 4) + lrow];
        b2r[n] = b2[(n << 4) + lrow];
    }
    __syncthreads();   // w2s ready; last barrier in the kernel

    __bf16* hw = hs[w];
    const f32x4 zero = {0.f, 0.f, 0.f, 0.f};

    const int gw = blockIdx.x * 8 + w;   // global wave id
    const int NW = NBLK * 8;
    const int NT = N_EDGES / 16;
    const int TPW = (NT + NW - 1) / NW;  // 25 tiles per wave
    const int tb0 = gw * TPW;
    if (tb0 >= NT) return;
    int tb1 = tb0 + TPW; if (tb1 > NT) tb1 = NT;

    #define GATHER(T, pv) do { \
        const float* fp_ = fij + (size_t)(pv) * NB; \
        if (kgrp < 3) { \
            T.f0 = *(const float4*)(fp_ + (kgrp << 3)); \
            T.f1 = *(const float4*)(fp_ + (kgrp << 3) + 4); \
        } else { \
            T.f0 = make_float4(fp_[24], 0.f, 0.f, 0.f); \
            T.f1 = make_float4(0.f, 0.f, 0.f, 0.f); \
        } \
        T.se_own = src[pv]; \
        T.de_own = dst[pv]; \
        T.rij_own = rij[pv]; \
    } while (0)

    TileReg cur, nxt;
    int pvB;
    {
        int pvA = perm[((size_t)tb0 << 4) + lrow];
        GATHER(cur, pvA);
        int i2 = tb0 + 1; i2 = (i2 < NT) ? i2 : (NT - 1);
        pvB = perm[((size_t)i2 << 4) + lrow];
    }

    int dcar = -1;        // carried dst row (wave-uniform)
    float scar[8];        // carried per-lane-group sums

    for (int tb = tb0; tb < tb1; ++tb) {
        // ---- (1) epilogue prep for CUR: shfls + xv loads FIRST (vmem head) ----
        float Cf_own = (cur.rij_own < CUTOFF_F)
                     ? 0.5f * (__cosf(cur.rij_own * PI_OVER_CUTOFF) + 1.0f) : 0.0f;
        int se4[4], de4[4]; float Cf[4];
        #pragma unroll
        for (int r = 0; r < 4; ++r) {
            se4[r] = __shfl(cur.se_own, (kgrp << 2) + r);
            Cf[r]  = __shfl(Cf_own, (kgrp << 2) + r);
            de4[r] = __shfl(cur.de_own, (kgrp << 2) + r);
        }
        bf16x8 xv4[4];
        #pragma unroll
        for (int r = 0; r < 4; ++r)
            xv4[r] = *(const bf16x8*)&xb[(size_t)se4[r] * FDIM + (lrow << 3)];

        // ---- (2) next-tile gathers AFTER xv (these pad xv's vmcnt slack) ----
        GATHER(nxt, pvB);
        int i3 = tb + 2; i3 = (i3 < NT) ? i3 : (NT - 1);
        pvB = perm[((size_t)i3 << 4) + lrow];

        // ---- (3) GEMM1: H = swish(fij_pad @ W1 + b1) -> hw (wave-local) ----
        bf16x8 a;
        a[0] = (__bf16)cur.f0.x; a[1] = (__bf16)cur.f0.y;
        a[2] = (__bf16)cur.f0.z; a[3] = (__bf16)cur.f0.w;
        a[4] = (__bf16)cur.f1.x; a[5] = (__bf16)cur.f1.y;
        a[6] = (__bf16)cur.f1.z; a[7] = (__bf16)cur.f1.w;

        #pragma unroll
        for (int n = 0; n < 8; ++n) {
            f32x4 h = __builtin_amdgcn_mfma_f32_16x16x32_bf16(a, w1f[n], zero, 0, 0, 0);
            #pragma unroll
            for (int r = 0; r < 4; ++r) {
                int hrow = (kgrp << 2) + r;
                float hv = swish_f(h[r] + b1r[n]);
                int byte = (hrow << 8) + (((n << 4) + lrow) << 1);
                byte ^= SWZ(hrow);
                *(__bf16*)((char*)hw + byte) = (__bf16)hv;
            }
        }
        // no barrier: hw is wave-local (same-wave DS ops are ordered)

        // ---- (4) GEMM2: Wfilt = H @ W2 (B-frags batched from LDS) ----
        f32x4 acc[8];
        #pragma unroll
        for (int n = 0; n < 8; ++n) acc[n] = zero;

        #pragma unroll
        for (int ks = 0; ks < 4; ++ks) {
            int byte = (lrow << 8) + (ks << 6) + (kgrp << 4);
            byte ^= SWZ(lrow);
            bf16x8 a2 = *(const bf16x8*)((const char*)hw + byte);
            bf16x8 bfr[8];
            #pragma unroll
            for (int n = 0; n < 8; ++n)
                bfr[n] = *(const bf16x8*)((const char*)w2s + (((ks << 3) + n) << 10) + (l << 4));
            #pragma unroll
            for (int n = 0; n < 8; ++n)
                acc[n] = __builtin_amdgcn_mfma_f32_16x16x32_bf16(a2, bfr[n], acc[n], 0, 0, 0);
        }

        // ---- (5) Epilogue: carry-merged uni path + run-compressed fallback ----
        int d0 = __shfl(cur.de_own, 0);
        bool uni = __all(cur.de_own == d0);

        if (uni) {
            float s8[8];
            #pragma unroll
            for (int n = 0; n < 8; ++n) {
                float s = 0.f;
                #pragma unroll
                for (int r = 0; r < 4; ++r)
                    s += (float)xv4[r][n] * (acc[n][r] + b2r[n]) * Cf[r];
                s += __shfl_xor(s, 16);
                s += __shfl_xor(s, 32);
                s8[n] = s;
            }
            if (d0 == dcar) {
                #pragma unroll
                for (int n = 0; n < 8; ++n) scar[n] += s8[n];
            } else {
                if (dcar >= 0 && kgrp == 0) {
                    const size_t cb = (size_t)dcar * FDIM;
                    #pragma unroll
                    for (int n = 0; n < 8; ++n)
                        unsafeAtomicAdd(&agg[cb + (n << 4) + lrow], scar[n]);
                }
                dcar = d0;
                #pragma unroll
                for (int n = 0; n < 8; ++n) scar[n] = s8[n];
            }
        } else {
            if (dcar >= 0 && kgrp == 0) {
                const size_t cb = (size_t)dcar * FDIM;
                #pragma unroll
                for (int n = 0; n < 8; ++n)
                    unsafeAtomicAdd(&agg[cb + (n << 4) + lrow], scar[n]);
            }
            dcar = -1;
            const bool brk0 = (de4[0] != de4[1]);
            const bool brk1 = (de4[1] != de4[2]);
            const bool brk2 = (de4[2] != de4[3]);
            #pragma unroll
            for (int n = 0; n < 8; ++n) {
                int col = (n << 4) + lrow;
                float m[4];
                #pragma unroll
                for (int r = 0; r < 4; ++r)
                    m[r] = (float)xv4[r][n] * (acc[n][r] + b2r[n]) * Cf[r];
                float run = m[0];
                if (brk0) { unsafeAtomicAdd(&agg[(size_t)de4[0] * FDIM + col], run); run = 0.f; }
                run += m[1];
                if (brk1) { unsafeAtomicAdd(&agg[(size_t)de4[1] * FDIM + col], run); run = 0.f; }
                run += m[2];
                if (brk2) { unsafeAtomicAdd(&agg[(size_t)de4[2] * FDIM + col], run); run = 0.f; }
                run += m[3];
                unsafeAtomicAdd(&agg[(size_t)de4[3] * FDIM + col], run);
            }
        }

        cur = nxt;
    }

    // final carry flush
    if (dcar >= 0 && kgrp == 0) {
        const size_t cb = (size_t)dcar * FDIM;
        #pragma unroll
        for (int n = 0; n < 8; ++n)
            unsafeAtomicAdd(&agg[cb + (n << 4) + lrow], scar[n]);
    }
    #undef GATHER
}

extern "C" void kernel_launch(void* const* d_in, const int* in_sizes, int n_in,
                              void* d_out, int out_size, void* d_ws, size_t ws_size,
                              hipStream_t stream)
{
    const float* feat   = (const float*)d_in[0];
    const float* fij    = (const float*)d_in[1];
    const float* rij    = (const float*)d_in[2];
    const int*   src    = (const int*)d_in[3];
    const int*   dst    = (const int*)d_in[4];
    const float* W_in2f = (const float*)d_in[5];
    const float* W_f1   = (const float*)d_in[6];
    const float* b_f1   = (const float*)d_in[7];
    const float* W_f2   = (const float*)d_in[8];
    const float* b_f2   = (const float*)d_in[9];
    const float* W_out  = (const float*)d_in[10];
    const float* b_out  = (const float*)d_in[11];
    float* out = (float*)d_out;

    // ws layout, total 33,333,696 B (r18-proven)
    char* ws = (char*)d_ws;
    __bf16* xb    = (__bf16*)ws;                  // 12,800,000 B
    __bf16* w1p   = (__bf16*)(ws + 12800000);     //      8,192 B
    __bf16* w2p   = (__bf16*)(ws + 12808192);     //     32,768 B
    __bf16* winp  = (__bf16*)(ws + 12840960);     //     32,768 B
    __bf16* woutp = (__bf16*)(ws + 12873728);     //     32,768 B
    int*    bt    = (int*)(ws + 12906496);        //      1,024 B (197 ints)
    int*    gh    = (int*)(ws + 12907520);        //    613,088 B
    int*    off   = (int*)(ws + 13520608);        //    613,088 B
    int*    ebkt  = (int*)(ws + 14133696);        //  6,400,000 B
    int*    ebuf1 = (int*)(ws + 20533696);        //  6,400,000 B
    int*    perm  = (int*)(ws + 26933696);        //  6,400,000 B
    float*  agg   = out;                          // accumulate into d_out

    hipMemsetAsync(agg, 0, (size_t)N_ATOMS * FDIM * sizeof(float), stream);

    // LDS-radix group-by-dst (no global atomics)
    radix1_hist_kernel<<<P1B, 256, 0, stream>>>(dst, ebkt, gh);
    scan_buckets_kernel<<<RB, 256, 0, stream>>>(gh, off, bt);
    scan_base_kernel<<<1, 256, 0, stream>>>(bt);
    radix1_place_kernel<<<P1B, 256, 0, stream>>>(ebkt, off, bt, ebuf1);
    radix2_kernel<<<RB, 1024, 0, stream>>>(ebuf1, dst, bt, perm);

    pack_b_kernel<<<(4096 + 255) / 256, 256, 0, stream>>>(W_f1, w1p, NB, 1);
    pack_b_kernel<<<(16384 + 255) / 256, 256, 0, stream>>>(W_f2, w2p, 128, 4);
    pack_b_kernel<<<(16384 + 255) / 256, 256, 0, stream>>>(W_in2f, winp, 128, 4);
    pack_b_kernel<<<(16384 + 255) / 256, 256, 0, stream>>>(W_out, woutp, 128, 4);

    // x = feat @ W_in2f  -> xb (bf16, permuted)
    node_mfma_kernel<<<(N_ATOMS / 16 + 7) / 8, 512, 0, stream>>>(
        feat, winp, nullptr, xb, nullptr, 0);

    edge_kernel<<<NBLK, 512, 0, stream>>>(
        fij, rij, src, dst, perm, w1p, b_f1, w2p, b_f2, xb, agg);

    // out = swish(agg @ W_out + b_out)  (in-place per 16-row tile)
    node_mfma_kernel<<<(N_ATOMS / 16 + 7) / 8, 512, 0, stream>>>(
        agg, woutp, b_out, nullptr, out, 1);
}